// Round 4
// baseline (332.897 us; speedup 1.0000x reference)
//
#include <hip/hip_runtime.h>

#define CH 64

// ---------------- build: per-dst linked list + out-degree histogram ---------
// next[e] = atomicExch(&head[dst[e]], e)  -- 1 random atomic + 1 coalesced write
__global__ void build_kernel(const int* __restrict__ src, const int* __restrict__ dst,
                             int* __restrict__ head, int* __restrict__ next,
                             int* __restrict__ outdeg, int E)
{
    int e = blockIdx.x * blockDim.x + threadIdx.x;
    if (e < E) {
        next[e] = atomicExch(&head[dst[e]], e);
        atomicAdd(&outdeg[src[e]], 1);
    }
}

// ---------------- aggregate raw x along chains: wave per node ----------------
// aggx[n] = sum_{e: dst=n} rsqrt(outdeg[src_e]) * x[src_e]; norm_dst[n] = rsqrt(deg)
__global__ __launch_bounds__(256) void agg_kernel(const float* __restrict__ x,
                                                  const int* __restrict__ src,
                                                  const int* __restrict__ head,
                                                  const int* __restrict__ next,
                                                  const int* __restrict__ outdeg,
                                                  float* __restrict__ aggx,
                                                  float* __restrict__ norm_dst, int N)
{
    int node = (blockIdx.x * blockDim.x + threadIdx.x) >> 6;
    int lane = threadIdx.x & 63;
    if (node >= N) return;
    float acc = 0.0f;
    int deg = 0;
    int e = __builtin_amdgcn_readfirstlane(head[node]);  // force scalar chain
    while (e >= 0) {
        int s  = __builtin_amdgcn_readfirstlane(src[e]);
        int en = __builtin_amdgcn_readfirstlane(next[e]);
        int od = outdeg[s];                  // >=1 (s is a source of edge e)
        float ns = rsqrtf((float)od);
        acc += ns * x[(size_t)s * CH + lane];
        ++deg;
        e = en;
    }
    aggx[(size_t)node * CH + lane] = acc;
    if (lane == 0) norm_dst[node] = (deg > 0) ? rsqrtf((float)deg) : 0.0f;
}

// ---------------- out = (aggx @ W) * norm_dst + bias  (row per thread) ------
__global__ __launch_bounds__(256) void gemm_out_kernel(const float* __restrict__ aggx,
                                                       const float* __restrict__ norm_dst,
                                                       const float* __restrict__ W,
                                                       const float* __restrict__ bias,
                                                       float* __restrict__ out, int N)
{
    int row = blockIdx.x * blockDim.x + threadIdx.x;
    if (row >= N) return;
    float nd = norm_dst[row];
    float xr[CH];
    const float4* xp = (const float4*)(aggx + (size_t)row * CH);
    #pragma unroll
    for (int j = 0; j < CH / 4; ++j) {
        float4 v = xp[j];
        xr[4 * j + 0] = v.x;
        xr[4 * j + 1] = v.y;
        xr[4 * j + 2] = v.z;
        xr[4 * j + 3] = v.w;
    }
    float* op = out + (size_t)row * CH;
    for (int c0 = 0; c0 < CH; c0 += 16) {
        float acc[16];
        #pragma unroll
        for (int q = 0; q < 16; ++q) acc[q] = 0.0f;
        #pragma unroll 8
        for (int k = 0; k < CH; ++k) {
            const float xk = xr[k];
            #pragma unroll
            for (int q = 0; q < 4; ++q) {
                float4 w = *(const float4*)(W + k * CH + c0 + q * 4);  // wave-uniform -> s_load
                acc[q * 4 + 0] += xk * w.x;
                acc[q * 4 + 1] += xk * w.y;
                acc[q * 4 + 2] += xk * w.z;
                acc[q * 4 + 3] += xk * w.w;
            }
        }
        #pragma unroll
        for (int q = 0; q < 4; ++q) {
            float4 b = *(const float4*)(bias + c0 + q * 4);  // wave-uniform
            float4 o;
            o.x = acc[q * 4 + 0] * nd + b.x;
            o.y = acc[q * 4 + 1] * nd + b.y;
            o.z = acc[q * 4 + 2] * nd + b.z;
            o.w = acc[q * 4 + 3] * nd + b.w;
            *(float4*)(op + c0 + q * 4) = o;
        }
    }
}

extern "C" void kernel_launch(void* const* d_in, const int* in_sizes, int n_in,
                              void* d_out, int out_size, void* d_ws, size_t ws_size,
                              hipStream_t stream)
{
    const float* x    = (const float*)d_in[0];
    const int*   edge = (const int*)d_in[1];
    const float* W    = (const float*)d_in[2];
    const float* bias = (const float*)d_in[3];
    float* out = (float*)d_out;

    int N = in_sizes[0] / CH;   // 100000
    int E = in_sizes[1] / 2;    // 1280000
    const int* src = edge;
    const int* dst = edge + E;

    // workspace: [head N][next E][outdeg N][norm_dst N floats][pad][aggx N*CH floats]
    int* head   = (int*)d_ws;
    int* next   = head + N;
    int* outdeg = next + E;
    float* norm_dst = (float*)(outdeg + N);
    size_t aoff = (((size_t)(3 * N + E) * sizeof(int)) + 255) & ~(size_t)255;
    float* aggx = (float*)((char*)d_ws + aoff);

    hipMemsetAsync(head, 0xFF, (size_t)N * sizeof(int), stream);      // head = -1
    hipMemsetAsync(outdeg, 0, (size_t)N * sizeof(int), stream);

    build_kernel<<<(E + 255) / 256, 256, 0, stream>>>(src, dst, head, next, outdeg, E);
    agg_kernel<<<((size_t)N * 64 + 255) / 256, 256, 0, stream>>>(x, src, head, next, outdeg,
                                                                 aggx, norm_dst, N);
    gemm_out_kernel<<<(N + 255) / 256, 256, 0, stream>>>(aggx, norm_dst, W, bias, out, N);
}

// Round 5
// 256.826 us; speedup vs baseline: 1.2962x; 1.2962x over previous
//
#include <hip/hip_runtime.h>
#include <hip/hip_fp16.h>

#define CH 64
#define SCAN_CHUNK 1024   // 256 threads x 4 elements
#define NPART 8           // one partition per XCD

// ---------------- partitioned degree histograms ------------------------------
// block b owns node-range partition (b & 7); round-robin dispatch pins that
// partition's 50 KB histogram slice in one XCD's L2 -> local atomics.
__global__ __launch_bounds__(256) void count_part_kernel(const int* __restrict__ src,
                                                         const int* __restrict__ dst,
                                                         int* __restrict__ outdeg,
                                                         int* __restrict__ indeg,
                                                         int E, int part)
{
    int p  = blockIdx.x & (NPART - 1);
    int gr = blockIdx.x >> 3;
    int gs = gridDim.x >> 3;
    int lo = p * part, hi = lo + part;
    for (int e = gr * 256 + threadIdx.x; e < E; e += gs * 256) {
        int s = src[e];
        int d = dst[e];
        if (s >= lo && s < hi) atomicAdd(&outdeg[s], 1);
        if (d >= lo && d < hi) atomicAdd(&indeg[d], 1);
    }
}

// ---------------- scan stage 1: per-block partial sums ----------------------
__global__ __launch_bounds__(256) void scan_partial_kernel(const int* __restrict__ indeg,
                                                           int* __restrict__ partial, int N)
{
    int tid = threadIdx.x;
    int base = blockIdx.x * SCAN_CHUNK + tid * 4;
    int s = 0;
    if (base + 3 < N) {
        int4 v = *(const int4*)(indeg + base);
        s = v.x + v.y + v.z + v.w;
    } else {
        for (int i = base; i < N && i < base + 4; ++i) s += indeg[i];
    }
    __shared__ int sm[256];
    sm[tid] = s;
    __syncthreads();
    for (int d = 128; d > 0; d >>= 1) {
        if (tid < d) sm[tid] += sm[tid + d];
        __syncthreads();
    }
    if (tid == 0) partial[blockIdx.x] = sm[0];
}

// ---------------- scan stage 2: exclusive scan of partials (NB <= 256) ------
__global__ __launch_bounds__(256) void scan_offsets_kernel(int* __restrict__ partial, int NB)
{
    __shared__ int sm[256];
    int tid = threadIdx.x;
    sm[tid] = (tid < NB) ? partial[tid] : 0;
    __syncthreads();
    for (int d = 1; d < 256; d <<= 1) {
        int v = (tid >= d) ? sm[tid - d] : 0;
        __syncthreads();
        sm[tid] += v;
        __syncthreads();
    }
    if (tid < NB) partial[tid] = (tid > 0) ? sm[tid - 1] : 0;
}

// ---------------- scan stage 3: write row_ptr AND cursor copy ---------------
__global__ __launch_bounds__(256) void scan_write_kernel(const int* __restrict__ indeg,
                                                         const int* __restrict__ partial,
                                                         int* __restrict__ row_ptr,
                                                         int* __restrict__ cursor, int N, int E)
{
    int tid = threadIdx.x;
    int base = blockIdx.x * SCAN_CHUNK + tid * 4;
    int v0 = 0, v1 = 0, v2 = 0, v3 = 0;
    if (base + 3 < N) {
        int4 v = *(const int4*)(indeg + base);
        v0 = v.x; v1 = v.y; v2 = v.z; v3 = v.w;
    } else {
        if (base + 0 < N) v0 = indeg[base + 0];
        if (base + 1 < N) v1 = indeg[base + 1];
        if (base + 2 < N) v2 = indeg[base + 2];
        if (base + 3 < N) v3 = indeg[base + 3];
    }
    __shared__ int sm[256];
    sm[tid] = v0 + v1 + v2 + v3;
    __syncthreads();
    for (int d = 1; d < 256; d <<= 1) {
        int t = (tid >= d) ? sm[tid - d] : 0;
        __syncthreads();
        sm[tid] += t;
        __syncthreads();
    }
    int off = partial[blockIdx.x] + ((tid > 0) ? sm[tid - 1] : 0);
    int o0 = off, o1 = off + v0, o2 = off + v0 + v1, o3 = off + v0 + v1 + v2;
    if (base + 0 < N) { row_ptr[base + 0] = o0; cursor[base + 0] = o0; }
    if (base + 1 < N) { row_ptr[base + 1] = o1; cursor[base + 1] = o1; }
    if (base + 2 < N) { row_ptr[base + 2] = o2; cursor[base + 2] = o2; }
    if (base + 3 < N) { row_ptr[base + 3] = o3; cursor[base + 3] = o3; }
    if (blockIdx.x == 0 && tid == 0) row_ptr[N] = E;
}

// ---------------- prescale: xh[n] = rsqrt(outdeg[n]) * x[n]  (fp16) ---------
__global__ __launch_bounds__(256) void prescale_kernel(const float* __restrict__ x,
                                                       const int* __restrict__ outdeg,
                                                       __half* __restrict__ xh, int N)
{
    int g = blockIdx.x * blockDim.x + threadIdx.x;   // one thread per 8 channels
    int total = N * (CH / 8);
    if (g >= total) return;
    int node = g >> 3, sub = g & 7;
    int od = outdeg[node];
    float ns = (od > 0) ? rsqrtf((float)od) : 0.0f;
    const float4* xp = (const float4*)(x + (size_t)node * CH + sub * 8);
    float4 a = xp[0], b = xp[1];
    __half2 h0 = __floats2half2_rn(a.x * ns, a.y * ns);
    __half2 h1 = __floats2half2_rn(a.z * ns, a.w * ns);
    __half2 h2 = __floats2half2_rn(b.x * ns, b.y * ns);
    __half2 h3 = __floats2half2_rn(b.z * ns, b.w * ns);
    uint4 u;
    u.x = (unsigned)__half_as_ushort(h0.x) | ((unsigned)__half_as_ushort(h0.y) << 16);
    u.y = (unsigned)__half_as_ushort(h1.x) | ((unsigned)__half_as_ushort(h1.y) << 16);
    u.z = (unsigned)__half_as_ushort(h2.x) | ((unsigned)__half_as_ushort(h2.y) << 16);
    u.w = (unsigned)__half_as_ushort(h3.x) | ((unsigned)__half_as_ushort(h3.y) << 16);
    *(uint4*)(xh + (size_t)node * CH + sub * 8) = u;
}

// ---------------- partitioned CSR fill --------------------------------------
// cursor slice + csr_src slice for partition p live in XCD p's L2.
__global__ __launch_bounds__(256) void fill_part_kernel(const int* __restrict__ src,
                                                        const int* __restrict__ dst,
                                                        int* __restrict__ cursor,
                                                        int* __restrict__ csr_src,
                                                        int E, int part)
{
    int p  = blockIdx.x & (NPART - 1);
    int gr = blockIdx.x >> 3;
    int gs = gridDim.x >> 3;
    int lo = p * part, hi = lo + part;
    for (int e = gr * 256 + threadIdx.x; e < E; e += gs * 256) {
        int d = dst[e];
        if (d >= lo && d < hi) {
            int pos = atomicAdd(&cursor[d], 1);
            csr_src[pos] = src[e];
        }
    }
}

// ---------------- aggregate: half-wave (32 lanes) per node, half2 per lane --
// aggx[n] = rsqrt(indeg_n) * sum_{e in N(n)} xh[src_e]
__global__ __launch_bounds__(256) void agg_kernel(const __half* __restrict__ xh,
                                                  const int* __restrict__ csr_src,
                                                  const int* __restrict__ row_ptr,
                                                  float* __restrict__ aggx, int N)
{
    int node = (blockIdx.x * blockDim.x + threadIdx.x) >> 5;
    int sl = threadIdx.x & 31;
    if (node >= N) return;
    int beg = row_ptr[node], end = row_ptr[node + 1];
    float ax0 = 0, ay0 = 0, ax1 = 0, ay1 = 0, ax2 = 0, ay2 = 0, ax3 = 0, ay3 = 0;
    int e = beg;
    for (; e + 4 <= end; e += 4) {
        int s0 = csr_src[e + 0], s1 = csr_src[e + 1];
        int s2 = csr_src[e + 2], s3 = csr_src[e + 3];
        float2 f0 = __half22float2(*(const __half2*)(xh + (size_t)s0 * CH + sl * 2));
        float2 f1 = __half22float2(*(const __half2*)(xh + (size_t)s1 * CH + sl * 2));
        float2 f2 = __half22float2(*(const __half2*)(xh + (size_t)s2 * CH + sl * 2));
        float2 f3 = __half22float2(*(const __half2*)(xh + (size_t)s3 * CH + sl * 2));
        ax0 += f0.x; ay0 += f0.y;
        ax1 += f1.x; ay1 += f1.y;
        ax2 += f2.x; ay2 += f2.y;
        ax3 += f3.x; ay3 += f3.y;
    }
    for (; e < end; ++e) {
        float2 f = __half22float2(*(const __half2*)(xh + (size_t)csr_src[e] * CH + sl * 2));
        ax0 += f.x; ay0 += f.y;
    }
    int deg = end - beg;
    float nd = (deg > 0) ? rsqrtf((float)deg) : 0.0f;
    float2 r;
    r.x = ((ax0 + ax1) + (ax2 + ax3)) * nd;
    r.y = ((ay0 + ay1) + (ay2 + ay3)) * nd;
    *(float2*)(aggx + (size_t)node * CH + sl * 2) = r;
}

// ---------------- out = aggx @ W + bias  (row per thread, W scalarized) -----
__global__ __launch_bounds__(256) void gemm_out_kernel(const float* __restrict__ aggx,
                                                       const float* __restrict__ W,
                                                       const float* __restrict__ bias,
                                                       float* __restrict__ out, int N)
{
    int row = blockIdx.x * blockDim.x + threadIdx.x;
    if (row >= N) return;
    float xr[CH];
    const float4* xp = (const float4*)(aggx + (size_t)row * CH);
    #pragma unroll
    for (int j = 0; j < CH / 4; ++j) {
        float4 v = xp[j];
        xr[4 * j + 0] = v.x;
        xr[4 * j + 1] = v.y;
        xr[4 * j + 2] = v.z;
        xr[4 * j + 3] = v.w;
    }
    float* op = out + (size_t)row * CH;
    for (int c0 = 0; c0 < CH; c0 += 16) {
        float acc[16];
        #pragma unroll
        for (int q = 0; q < 16; ++q) acc[q] = 0.0f;
        #pragma unroll 8
        for (int k = 0; k < CH; ++k) {
            const float xk = xr[k];
            #pragma unroll
            for (int q = 0; q < 4; ++q) {
                float4 w = *(const float4*)(W + k * CH + c0 + q * 4);  // wave-uniform -> s_load
                acc[q * 4 + 0] += xk * w.x;
                acc[q * 4 + 1] += xk * w.y;
                acc[q * 4 + 2] += xk * w.z;
                acc[q * 4 + 3] += xk * w.w;
            }
        }
        #pragma unroll
        for (int q = 0; q < 4; ++q) {
            float4 b = *(const float4*)(bias + c0 + q * 4);  // wave-uniform
            float4 o;
            o.x = acc[q * 4 + 0] + b.x;
            o.y = acc[q * 4 + 1] + b.y;
            o.z = acc[q * 4 + 2] + b.z;
            o.w = acc[q * 4 + 3] + b.w;
            *(float4*)(op + c0 + q * 4) = o;
        }
    }
}

extern "C" void kernel_launch(void* const* d_in, const int* in_sizes, int n_in,
                              void* d_out, int out_size, void* d_ws, size_t ws_size,
                              hipStream_t stream)
{
    const float* x    = (const float*)d_in[0];
    const int*   edge = (const int*)d_in[1];
    const float* W    = (const float*)d_in[2];
    const float* bias = (const float*)d_in[3];
    float* out = (float*)d_out;

    int N = in_sizes[0] / CH;   // 100000
    int E = in_sizes[1] / 2;    // 1280000
    const int* src = edge;
    const int* dst = edge + E;
    int part = (N + NPART - 1) / NPART;   // 12500

    // workspace (ints 4B):
    // [outdeg N][indeg N][row_ptr N+1][pad][cursor N][partial 256][csr_src E]
    // [pad][xh N*CH halves][pad][aggx N*CH floats]
    int* base = (int*)d_ws;
    int* outdeg  = base;
    int* indeg   = base + N;
    int* row_ptr = base + 2 * N;
    int* cursor  = base + 3 * N + 64;
    int* partial = base + 4 * N + 128;
    int* csr_src = base + 4 * N + 128 + 256;
    size_t xoff = (((size_t)(4 * N + 128 + 256 + E) * sizeof(int)) + 255) & ~(size_t)255;
    __half* xh = (__half*)((char*)d_ws + xoff);
    size_t aoff = ((xoff + (size_t)N * CH * sizeof(__half)) + 255) & ~(size_t)255;
    float* aggx = (float*)((char*)d_ws + aoff);

    hipMemsetAsync(base, 0, (size_t)2 * N * sizeof(int), stream);  // outdeg+indeg

    int NB = (N + SCAN_CHUNK - 1) / SCAN_CHUNK;  // 98 <= 256
    count_part_kernel<<<2048, 256, 0, stream>>>(src, dst, outdeg, indeg, E, part);
    scan_partial_kernel<<<NB, 256, 0, stream>>>(indeg, partial, N);
    scan_offsets_kernel<<<1, 256, 0, stream>>>(partial, NB);
    scan_write_kernel<<<NB, 256, 0, stream>>>(indeg, partial, row_ptr, cursor, N, E);
    prescale_kernel<<<(N * (CH / 8) + 255) / 256, 256, 0, stream>>>(x, outdeg, xh, N);
    fill_part_kernel<<<2048, 256, 0, stream>>>(src, dst, cursor, csr_src, E, part);
    agg_kernel<<<((size_t)N * 32 + 255) / 256, 256, 0, stream>>>(xh, csr_src, row_ptr, aggx, N);
    gemm_out_kernel<<<(N + 255) / 256, 256, 0, stream>>>(aggx, W, bias, out, N);
}

// Round 6
// 205.098 us; speedup vs baseline: 1.6231x; 1.2522x over previous
//
#include <hip/hip_runtime.h>
#include <hip/hip_fp16.h>

#define CH 64
#define CAP 40        // bucket capacity; indeg ~ Poisson(12.8), P(>=40) ~ 7e-10
#define SPILLMAX 4096

// ---------------- build: bucket fill by dst + outdeg histogram, one pass ----
// cursor cnt[d] doubles as the indeg histogram -> no count kernel, no scan.
__global__ __launch_bounds__(256) void build_kernel(const int* __restrict__ src,
                                                    const int* __restrict__ dst,
                                                    int* __restrict__ cnt,
                                                    int* __restrict__ outdeg,
                                                    int* __restrict__ bucket,
                                                    int* __restrict__ spill,
                                                    int* __restrict__ nspill, int E)
{
    int e = blockIdx.x * blockDim.x + threadIdx.x;
    if (e >= E) return;
    int s = src[e];
    int d = dst[e];
    atomicAdd(&outdeg[s], 1);
    int pos = atomicAdd(&cnt[d], 1);
    if (pos < CAP) {
        bucket[(size_t)d * CAP + pos] = s;
    } else {                       // statistically never on this data
        int sp = atomicAdd(nspill, 1);
        if (sp < SPILLMAX) { spill[2 * sp] = d; spill[2 * sp + 1] = s; }
    }
}

// ---------------- prescale: xh[n] = rsqrt(outdeg[n]) * x[n]  (fp16) ---------
__global__ __launch_bounds__(256) void prescale_kernel(const float* __restrict__ x,
                                                       const int* __restrict__ outdeg,
                                                       __half* __restrict__ xh, int N)
{
    int g = blockIdx.x * blockDim.x + threadIdx.x;   // one thread per 8 channels
    int total = N * (CH / 8);
    if (g >= total) return;
    int node = g >> 3, sub = g & 7;
    int od = outdeg[node];
    float ns = (od > 0) ? rsqrtf((float)od) : 0.0f;
    const float4* xp = (const float4*)(x + (size_t)node * CH + sub * 8);
    float4 a = xp[0], b = xp[1];
    __half2 h0 = __floats2half2_rn(a.x * ns, a.y * ns);
    __half2 h1 = __floats2half2_rn(a.z * ns, a.w * ns);
    __half2 h2 = __floats2half2_rn(b.x * ns, b.y * ns);
    __half2 h3 = __floats2half2_rn(b.z * ns, b.w * ns);
    uint4 u;
    u.x = (unsigned)__half_as_ushort(h0.x) | ((unsigned)__half_as_ushort(h0.y) << 16);
    u.y = (unsigned)__half_as_ushort(h1.x) | ((unsigned)__half_as_ushort(h1.y) << 16);
    u.z = (unsigned)__half_as_ushort(h2.x) | ((unsigned)__half_as_ushort(h2.y) << 16);
    u.w = (unsigned)__half_as_ushort(h3.x) | ((unsigned)__half_as_ushort(h3.y) << 16);
    *(uint4*)(xh + (size_t)node * CH + sub * 8) = u;
}

// ---------------- aggregate: half-wave (32 lanes) per node, half2 per lane --
// aggh[n] = fp16( rsqrt(cnt_n) * sum_{e in bucket(n)} xh[src_e] )
__global__ __launch_bounds__(256) void agg_kernel(const __half* __restrict__ xh,
                                                  const int* __restrict__ bucket,
                                                  const int* __restrict__ cnt,
                                                  const int* __restrict__ spill,
                                                  const int* __restrict__ nspill,
                                                  __half* __restrict__ aggh, int N)
{
    int node = (blockIdx.x * blockDim.x + threadIdx.x) >> 5;
    int sl = threadIdx.x & 31;
    if (node >= N) return;
    int c = cnt[node];
    int m = (c < CAP) ? c : CAP;
    const int* bp = bucket + (size_t)node * CAP;
    float ax0 = 0, ay0 = 0, ax1 = 0, ay1 = 0, ax2 = 0, ay2 = 0, ax3 = 0, ay3 = 0;
    int j = 0;
    for (; j + 4 <= m; j += 4) {
        int s0 = bp[j + 0], s1 = bp[j + 1], s2 = bp[j + 2], s3 = bp[j + 3];
        float2 f0 = __half22float2(*(const __half2*)(xh + (size_t)s0 * CH + sl * 2));
        float2 f1 = __half22float2(*(const __half2*)(xh + (size_t)s1 * CH + sl * 2));
        float2 f2 = __half22float2(*(const __half2*)(xh + (size_t)s2 * CH + sl * 2));
        float2 f3 = __half22float2(*(const __half2*)(xh + (size_t)s3 * CH + sl * 2));
        ax0 += f0.x; ay0 += f0.y;
        ax1 += f1.x; ay1 += f1.y;
        ax2 += f2.x; ay2 += f2.y;
        ax3 += f3.x; ay3 += f3.y;
    }
    for (; j < m; ++j) {
        float2 f = __half22float2(*(const __half2*)(xh + (size_t)bp[j] * CH + sl * 2));
        ax0 += f.x; ay0 += f.y;
    }
    if (c > CAP) {   // cold spill sweep (keeps any-input correctness)
        int ns = *nspill;
        if (ns > SPILLMAX) ns = SPILLMAX;
        for (int i = 0; i < ns; ++i) {
            if (spill[2 * i] == node) {
                float2 f = __half22float2(*(const __half2*)(xh + (size_t)spill[2 * i + 1] * CH + sl * 2));
                ax0 += f.x; ay0 += f.y;
            }
        }
    }
    float nd = (c > 0) ? rsqrtf((float)c) : 0.0f;
    float rx = ((ax0 + ax1) + (ax2 + ax3)) * nd;
    float ry = ((ay0 + ay1) + (ay2 + ay3)) * nd;
    *(__half2*)(aggh + (size_t)node * CH + sl * 2) = __floats2half2_rn(rx, ry);
}

// ---------------- out = aggh @ W + bias  (row per thread, W scalarized) -----
__global__ __launch_bounds__(256) void gemm_out_kernel(const __half* __restrict__ aggh,
                                                       const float* __restrict__ W,
                                                       const float* __restrict__ bias,
                                                       float* __restrict__ out, int N)
{
    int row = blockIdx.x * blockDim.x + threadIdx.x;
    if (row >= N) return;
    float xr[CH];
    const __half2* xp = (const __half2*)(aggh + (size_t)row * CH);
    #pragma unroll
    for (int j = 0; j < CH / 2; ++j) {
        float2 f = __half22float2(xp[j]);
        xr[2 * j + 0] = f.x;
        xr[2 * j + 1] = f.y;
    }
    float* op = out + (size_t)row * CH;
    for (int c0 = 0; c0 < CH; c0 += 16) {
        float acc[16];
        #pragma unroll
        for (int q = 0; q < 16; ++q) acc[q] = 0.0f;
        #pragma unroll 8
        for (int k = 0; k < CH; ++k) {
            const float xk = xr[k];
            #pragma unroll
            for (int q = 0; q < 4; ++q) {
                float4 w = *(const float4*)(W + k * CH + c0 + q * 4);  // wave-uniform -> s_load
                acc[q * 4 + 0] += xk * w.x;
                acc[q * 4 + 1] += xk * w.y;
                acc[q * 4 + 2] += xk * w.z;
                acc[q * 4 + 3] += xk * w.w;
            }
        }
        #pragma unroll
        for (int q = 0; q < 4; ++q) {
            float4 b = *(const float4*)(bias + c0 + q * 4);  // wave-uniform
            float4 o;
            o.x = acc[q * 4 + 0] + b.x;
            o.y = acc[q * 4 + 1] + b.y;
            o.z = acc[q * 4 + 2] + b.z;
            o.w = acc[q * 4 + 3] + b.w;
            *(float4*)(op + c0 + q * 4) = o;
        }
    }
}

extern "C" void kernel_launch(void* const* d_in, const int* in_sizes, int n_in,
                              void* d_out, int out_size, void* d_ws, size_t ws_size,
                              hipStream_t stream)
{
    const float* x    = (const float*)d_in[0];
    const int*   edge = (const int*)d_in[1];
    const float* W    = (const float*)d_in[2];
    const float* bias = (const float*)d_in[3];
    float* out = (float*)d_out;

    int N = in_sizes[0] / CH;   // 100000
    int E = in_sizes[1] / 2;    // 1280000
    const int* src = edge;
    const int* dst = edge + E;

    // workspace (ints 4B):
    // [cnt N][outdeg N][nspill 1, pad 64][spill 2*SPILLMAX][bucket N*CAP]
    // [pad][xh N*CH halves][pad][aggh N*CH halves]            (~43 MB total)
    int* cnt    = (int*)d_ws;
    int* outdeg = cnt + N;
    int* nspill = outdeg + N;
    int* spill  = nspill + 64;
    int* bucket = spill + 2 * SPILLMAX;
    size_t xoff = (((char*)(bucket + (size_t)N * CAP) - (char*)d_ws) + 255) & ~(size_t)255;
    __half* xh = (__half*)((char*)d_ws + xoff);
    size_t aoff = ((xoff + (size_t)N * CH * sizeof(__half)) + 255) & ~(size_t)255;
    __half* aggh = (__half*)((char*)d_ws + aoff);

    // zero cnt + outdeg + nspill (contiguous)
    hipMemsetAsync(cnt, 0, ((size_t)2 * N + 64) * sizeof(int), stream);

    build_kernel<<<(E + 255) / 256, 256, 0, stream>>>(src, dst, cnt, outdeg, bucket,
                                                      spill, nspill, E);
    prescale_kernel<<<(N * (CH / 8) + 255) / 256, 256, 0, stream>>>(x, outdeg, xh, N);
    agg_kernel<<<((size_t)N * 32 + 255) / 256, 256, 0, stream>>>(xh, bucket, cnt, spill,
                                                                 nspill, aggh, N);
    gemm_out_kernel<<<(N + 255) / 256, 256, 0, stream>>>(aggh, W, bias, out, N);
}